// Round 4
// baseline (569.378 us; speedup 1.0000x reference)
//
#include <hip/hip_runtime.h>
#include <hip/hip_bf16.h>
#include <stdint.h>

// QuantizedLinear NF4: x (4,2048,4096) f32, packed (4096,2048) i32 (one byte
// per int32), absmax (4096,) f32, bias (4096,) f32 -> out (4,2048,4096) f32.
#define M_DIM 8192
#define N_DIM 4096
#define K_DIM 4096

typedef __bf16 bf16_t;
typedef __attribute__((ext_vector_type(8))) __bf16 bf16x8;
typedef __attribute__((ext_vector_type(4))) __bf16 bf16x4;
typedef __attribute__((ext_vector_type(4))) float f32x4;

__constant__ float NF4_LUT[16] = {
    -1.0f, -0.6961928009986877f, -0.5250730514526367f, -0.39491748809814453f,
    -0.28444138169288635f, -0.18477343022823334f, -0.09105003625154495f, 0.0f,
    0.07958029955625534f, 0.16093020141124725f, 0.24611230194568634f,
    0.33791524171829224f, 0.44070982933044434f, 0.5626170039176941f,
    0.7229568362236023f, 1.0f};

// ---------------------------------------------------------------------------
// Kernel 1 (fused): NF4 dequant -> bf16 W  AND  x f32 -> bf16.
// ---------------------------------------------------------------------------
#define DQ_BLOCKS ((N_DIM * (K_DIM / 2) / 4) / 256)   // 8192
#define CVT_BLOCKS ((M_DIM * K_DIM / 4) / 256)        // 8192

__global__ __launch_bounds__(256) void prep_kernel(
    const int* __restrict__ packed, const float* __restrict__ absmax,
    bf16_t* __restrict__ W, const float* __restrict__ x,
    bf16_t* __restrict__ y) {
  if (blockIdx.x < DQ_BLOCKS) {
    const int t = blockIdx.x * 256 + threadIdx.x;
    const int row = t >> 9;
    const int c = t & 511;
    const int lane = threadIdx.x & 63;
    const int lutbits = __float_as_int(NF4_LUT[lane & 15]);

    const int4 p = ((const int4*)packed)[t];
    const float am = absmax[row];
    bf16x8 v;
#pragma unroll
    for (int q = 0; q < 4; ++q) {
      const int byte = (q == 0 ? p.x : q == 1 ? p.y : q == 2 ? p.z : p.w) & 255;
      const float hi = __int_as_float(
          __builtin_amdgcn_ds_bpermute(((byte >> 4) & 15) << 2, lutbits));
      const float lo = __int_as_float(
          __builtin_amdgcn_ds_bpermute((byte & 15) << 2, lutbits));
      v[2 * q] = (bf16_t)(hi * am);
      v[2 * q + 1] = (bf16_t)(lo * am);
    }
    *((bf16x8*)&W[(size_t)row * K_DIM + c * 8]) = v;
  } else {
    const int t = (blockIdx.x - DQ_BLOCKS) * 256 + threadIdx.x;
    const float4 a = ((const float4*)x)[t];
    bf16x4 v;
    v[0] = (bf16_t)a.x; v[1] = (bf16_t)a.y;
    v[2] = (bf16_t)a.z; v[3] = (bf16_t)a.w;
    *((bf16x4*)&y[(size_t)t * 4]) = v;
  }
}

// ---------------------------------------------------------------------------
// Kernel 2: 256x256x64 bf16 MFMA GEMM, 16x16x32, compiler-scheduled waits.
//
// Round-4 change vs round 3: the explicit lgkmcnt(0)+sched_barrier(0) fences
// are REMOVED — all LDS reads are plain C++ loads, so the compiler tracks
// deps in SSA and emits counted lgkmcnt per use (rule #18 applies only to
// inline-asm ds_read, which we do not use). The second A-half's 8 reads are
// issued BETWEEN MFMA sub-clusters via register-slot reuse, so DS latency
// hides under MFMA without growing fragment registers past round 3's 64.
//
// LDS: [2 buf][256 rows][8 chunks of 16B], phys chunk = logical ^ (row&7).
// Linear LDS dest for global_load_lds; pre-swizzled GLOBAL source.
// Fragment-read geometry: row = base + i*16 + l15, slot = (kc*4+quad)^l7 —
// measured 0 bank conflicts (rounds 1/3); round-2's l31-based geometry
// measured 2.5e7 — do not reintroduce.
//
// Per K-tile t (2 barriers, counted vmcnt — structure identical to round 3):
//   pre : read af0-3 (A1 part, 8x b128) + bq (B1+B2, 8x b128);
//         stage A2B2(t+1) -> other buf (dead since t-1's S2/end-barrier).
//   MID-BARRIER  (all waves' A1/B1(cur) reads issued before any staging in).
//   stage A1B1(t+2) -> cur buf.
//   S1a: 16 MFMA (i=0,1);  reload slots 0,1 <- A2 frags 4,5;
//   S1b: 16 MFMA (i=2,3);  reload slots 2,3 <- A2 frags 6,7;
//   S2a: 16 MFMA (acc[4..5]); S2b: 16 MFMA (acc[6..7]).
//   vmcnt(4): retires A1B1(t+1)+A2B2(t+1) (in-order FIFO), keeps A1B1(t+2)
//   in flight — never vmcnt(0) mid-loop.  END-BARRIER.
// ---------------------------------------------------------------------------
#define GLD_LDS16(g, l)                                                     \
  __builtin_amdgcn_global_load_lds(                                        \
      (const __attribute__((address_space(1))) void*)(g),                   \
      (__attribute__((address_space(3))) void*)(l), 16, 0, 0)

#define MFMA16(a, b, c) \
  __builtin_amdgcn_mfma_f32_16x16x32_bf16((a), (b), (c), 0, 0, 0)

#define STAGE_A1(tt, lds)                                    \
  do {                                                       \
    GLD_LDS16(gA1a + (size_t)(tt) * 64, (lds) + dA0);        \
    GLD_LDS16(gA1b + (size_t)(tt) * 64, (lds) + dA0 + 16384);\
  } while (0)
#define STAGE_A2(tt, lds)                                    \
  do {                                                       \
    GLD_LDS16(gA2a + (size_t)(tt) * 64, (lds) + dA0 + 8192); \
    GLD_LDS16(gA2b + (size_t)(tt) * 64, (lds) + dA0 + 24576);\
  } while (0)
#define STAGE_B1(tt, lds)                                    \
  do {                                                       \
    GLD_LDS16(gB1a + (size_t)(tt) * 64, (lds) + dB0);        \
    GLD_LDS16(gB1b + (size_t)(tt) * 64, (lds) + dB0 + 16384);\
  } while (0)
#define STAGE_B2(tt, lds)                                    \
  do {                                                       \
    GLD_LDS16(gB2a + (size_t)(tt) * 64, (lds) + dB0 + 4096); \
    GLD_LDS16(gB2b + (size_t)(tt) * 64, (lds) + dB0 + 20480);\
  } while (0)

#define BARRIER()                    \
  asm volatile("" ::: "memory");     \
  __builtin_amdgcn_s_barrier();      \
  asm volatile("" ::: "memory")

__global__ __launch_bounds__(512, 2) void gemm_nf4_kernel(
    const bf16_t* __restrict__ A, const bf16_t* __restrict__ B,
    const float* __restrict__ bias, float* __restrict__ C) {
  constexpr int NT = K_DIM / 64;
  __shared__ __align__(16) bf16_t sA[2][256 * 64];  // 2 x 32 KiB
  __shared__ __align__(16) bf16_t sB[2][256 * 64];  // 2 x 32 KiB

  const int tid = threadIdx.x;
  const int wave = tid >> 6, lane = tid & 63;
  const int wm = wave >> 2, wn = wave & 3;  // 2 x 4 wave grid
  const int quad = lane >> 4, l15 = lane & 15, l7 = lane & 7;

  // T1: XCD-aware block swizzle (512 blocks, 512 % 8 == 0 -> bijective).
  const int id = (blockIdx.x & 7) * 64 + (blockIdx.x >> 3);
  const int blockM = (id & 31) * 256;  // 32 M-blocks
  const int blockN = (id >> 5) * 256;  // 16 N-blocks

  // ---- staging addresses (linear LDS dest, pre-swizzled global source) ----
  const int rqa = tid >> 3;                       // row in 64-row quarter
  const int cira = ((tid & 7) ^ (rqa & 7)) * 8;   // swizzled chunk -> elements
  const bf16_t* gA1a = A + (size_t)(blockM + rqa) * K_DIM + cira;
  const bf16_t* gA1b = gA1a + (size_t)128 * K_DIM;
  const bf16_t* gA2a = gA1a + (size_t)64 * K_DIM;
  const bf16_t* gA2b = gA1a + (size_t)192 * K_DIM;
  const int s0 = tid >> 8, cis = tid & 255;       // B: strip, chunk-in-strip
  const int rqb = cis >> 3;                       // row in 32-row strip
  const int cirb = ((cis & 7) ^ (rqb & 7)) * 8;
  const bf16_t* gB1a = B + (size_t)(blockN + s0 * 64 + rqb) * K_DIM + cirb;
  const bf16_t* gB1b = gB1a + (size_t)128 * K_DIM;
  const bf16_t* gB2a = gB1a + (size_t)32 * K_DIM;
  const bf16_t* gB2b = gB1a + (size_t)160 * K_DIM;
  const int dA0 = tid * 16;
  const int dB0 = s0 * 8192 + cis * 16;

  // ---- fragment-read byte offsets (0-conflict geometry, rounds 1/3) ----
  const int aBase = (wm * 128 + l15) * 128;
  const int bBase = (wn * 64 + l15) * 128;
  const int sl0 = (quad ^ l7) * 16;        // kc = 0
  const int sl1 = ((4 | quad) ^ l7) * 16;  // kc = 1

  f32x4 acc[8][4];
#pragma unroll
  for (int i = 0; i < 8; ++i)
#pragma unroll
    for (int j = 0; j < 4; ++j) acc[i][j] = (f32x4)(0.0f);

  // ---- prologue: tile 0 fully + tile 1's A1/B1 groups ----
  {
    char* sa0 = (char*)sA[0];
    char* sb0 = (char*)sB[0];
    char* sa1 = (char*)sA[1];
    char* sb1 = (char*)sB[1];
    STAGE_A1(0, sa0);
    STAGE_B1(0, sb0);
    STAGE_A2(0, sa0);
    STAGE_B2(0, sb0);
    STAGE_A1(1, sa1);
    STAGE_B1(1, sb1);
    asm volatile("s_waitcnt vmcnt(4)" ::: "memory");  // tile 0 resident
    __builtin_amdgcn_s_barrier();
    asm volatile("" ::: "memory");
  }

  for (int t = 0; t < NT; ++t) {
    char* sa = (char*)sA[t & 1];
    char* sao = (char*)sA[(t + 1) & 1];
    char* sb = (char*)sB[t & 1];
    char* sbo = (char*)sB[(t + 1) & 1];

    bf16x8 af[4][2], bq[4][2];

    // ---- pre-barrier: A1-half frags + all B frags; stage A2B2(t+1) ----
#pragma unroll
    for (int i = 0; i < 4; ++i) {
      af[i][0] = *(const bf16x8*)(sa + aBase + i * 2048 + sl0);
      af[i][1] = *(const bf16x8*)(sa + aBase + i * 2048 + sl1);
    }
#pragma unroll
    for (int j = 0; j < 4; ++j) {
      bq[j][0] = *(const bf16x8*)(sb + bBase + j * 2048 + sl0);
      bq[j][1] = *(const bf16x8*)(sb + bBase + j * 2048 + sl1);
    }
    if (t + 1 < NT) {
      STAGE_A2(t + 1, sao);
      STAGE_B2(t + 1, sbo);
    }
    BARRIER();  // mid: all waves' A1/B1(cur) reads issued

    if (t + 2 < NT) {
      STAGE_A1(t + 2, sa);
      STAGE_B1(t + 2, sb);
    }

    __builtin_amdgcn_s_setprio(1);
    // S1a: i = 0,1 (16 MFMA) — compiler waits only on af0/af1/bq.
#pragma unroll
    for (int i = 0; i < 2; ++i)
#pragma unroll
      for (int j = 0; j < 4; ++j) {
        acc[i][j] = MFMA16(af[i][0], bq[j][0], acc[i][j]);
        acc[i][j] = MFMA16(af[i][1], bq[j][1], acc[i][j]);
      }
    // reload slots 0,1 <- A2 frags (rows +64): latency hides under S1b.
#pragma unroll
    for (int i = 0; i < 2; ++i) {
      af[i][0] = *(const bf16x8*)(sa + aBase + 8192 + i * 2048 + sl0);
      af[i][1] = *(const bf16x8*)(sa + aBase + 8192 + i * 2048 + sl1);
    }
    // S1b: i = 2,3 (16 MFMA).
#pragma unroll
    for (int i = 2; i < 4; ++i)
#pragma unroll
      for (int j = 0; j < 4; ++j) {
        acc[i][j] = MFMA16(af[i][0], bq[j][0], acc[i][j]);
        acc[i][j] = MFMA16(af[i][1], bq[j][1], acc[i][j]);
      }
    // reload slots 2,3 <- A2 frags 6,7: latency hides under S2a.
#pragma unroll
    for (int i = 2; i < 4; ++i) {
      af[i][0] = *(const bf16x8*)(sa + aBase + 8192 + i * 2048 + sl0);
      af[i][1] = *(const bf16x8*)(sa + aBase + 8192 + i * 2048 + sl1);
    }
    // S2a: logical i = 4,5 (slots 0,1).
#pragma unroll
    for (int i = 0; i < 2; ++i)
#pragma unroll
      for (int j = 0; j < 4; ++j) {
        acc[4 + i][j] = MFMA16(af[i][0], bq[j][0], acc[4 + i][j]);
        acc[4 + i][j] = MFMA16(af[i][1], bq[j][1], acc[4 + i][j]);
      }
    // S2b: logical i = 6,7 (slots 2,3).
#pragma unroll
    for (int i = 2; i < 4; ++i)
#pragma unroll
      for (int j = 0; j < 4; ++j) {
        acc[4 + i][j] = MFMA16(af[i][0], bq[j][0], acc[4 + i][j]);
        acc[4 + i][j] = MFMA16(af[i][1], bq[j][1], acc[4 + i][j]);
      }
    __builtin_amdgcn_s_setprio(0);

    // Counted vmcnt (T4): retire tile-(t+1) staging (FIFO: A1B1(t+1) then
    // A2B2(t+1)), keep A1B1(t+2) in flight. Full drain only at the tail.
    if (t < NT - 2)
      asm volatile("s_waitcnt vmcnt(4)" ::: "memory");
    else
      asm volatile("s_waitcnt vmcnt(0)" ::: "memory");
    BARRIER();
  }

  // ---- epilogue: C/D layout col = l15 (n), row = quad*4 + reg (m) ----
#pragma unroll
  for (int j = 0; j < 4; ++j) {
    const int n = blockN + wn * 64 + j * 16 + l15;
    const float bv = bias[n];
#pragma unroll
    for (int i = 0; i < 8; ++i) {
      const int m0 = blockM + wm * 128 + i * 16 + quad * 4;
      f32x4 v = acc[i][j];
      C[(size_t)(m0 + 0) * N_DIM + n] = v[0] + bv;
      C[(size_t)(m0 + 1) * N_DIM + n] = v[1] + bv;
      C[(size_t)(m0 + 2) * N_DIM + n] = v[2] + bv;
      C[(size_t)(m0 + 3) * N_DIM + n] = v[3] + bv;
    }
  }
}

// ---------------------------------------------------------------------------
// Fallback (ws too small): naive on-the-fly dequant GEMM.
// ---------------------------------------------------------------------------
__global__ __launch_bounds__(256) void fallback_kernel(
    const float* __restrict__ x, const int* __restrict__ packed,
    const float* __restrict__ absmax, const float* __restrict__ bias,
    float* __restrict__ out) {
  const int idx = blockIdx.x * 256 + threadIdx.x;
  const int m = idx / N_DIM, n = idx % N_DIM;
  const int* prow = packed + (size_t)n * (K_DIM / 2);
  const float* xr = x + (size_t)m * K_DIM;
  float s = 0.0f;
  for (int p = 0; p < K_DIM / 2; ++p) {
    const int b = prow[p] & 255;
    s += xr[2 * p] * NF4_LUT[(b >> 4) & 15] + xr[2 * p + 1] * NF4_LUT[b & 15];
  }
  out[idx] = s * absmax[n] + bias[n];
}

extern "C" void kernel_launch(void* const* d_in, const int* in_sizes, int n_in,
                              void* d_out, int out_size, void* d_ws,
                              size_t ws_size, hipStream_t stream) {
  const float* x = (const float*)d_in[0];
  const int* packed = (const int*)d_in[1];
  const float* absmax = (const float*)d_in[2];
  const float* bias = (const float*)d_in[3];
  float* out = (float*)d_out;

  const size_t wBytes = (size_t)N_DIM * K_DIM * sizeof(bf16_t);  // 32 MB
  const size_t xBytes = (size_t)M_DIM * K_DIM * sizeof(bf16_t);  // 64 MB
  if (ws_size < wBytes + xBytes) {
    fallback_kernel<<<dim3((M_DIM * N_DIM) / 256), dim3(256), 0, stream>>>(
        x, packed, absmax, bias, out);
    return;
  }

  bf16_t* W = (bf16_t*)d_ws;
  bf16_t* xb = (bf16_t*)((char*)d_ws + wBytes);

  prep_kernel<<<dim3(DQ_BLOCKS + CVT_BLOCKS), dim3(256), 0, stream>>>(
      packed, absmax, W, x, xb);
  gemm_nf4_kernel<<<dim3((M_DIM / 256) * (N_DIM / 256)), dim3(512), 0,
                    stream>>>(xb, W, bias, out);
}

// Round 9
// 496.276 us; speedup vs baseline: 1.1473x; 1.1473x over previous
//
#include <hip/hip_runtime.h>
#include <hip/hip_bf16.h>
#include <stdint.h>

// QuantizedLinear NF4: x (4,2048,4096) f32, packed (4096,2048) i32 (one byte
// per int32), absmax (4096,) f32, bias (4096,) f32 -> out (4,2048,4096) f32.
#define M_DIM 8192
#define N_DIM 4096
#define K_DIM 4096

typedef __bf16 bf16_t;
typedef __attribute__((ext_vector_type(8))) __bf16 bf16x8;
typedef __attribute__((ext_vector_type(4))) __bf16 bf16x4;
typedef __attribute__((ext_vector_type(4))) float f32x4;

__constant__ float NF4_LUT[16] = {
    -1.0f, -0.6961928009986877f, -0.5250730514526367f, -0.39491748809814453f,
    -0.28444138169288635f, -0.18477343022823334f, -0.09105003625154495f, 0.0f,
    0.07958029955625534f, 0.16093020141124725f, 0.24611230194568634f,
    0.33791524171829224f, 0.44070982933044434f, 0.5626170039176941f,
    0.7229568362236023f, 1.0f};

// ---------------------------------------------------------------------------
// Kernel 1 (fused, grid-stride): NF4 dequant -> bf16 W, then x f32 -> bf16.
// 2048 blocks (G11: memory-bound cap ~2048 + grid-stride) instead of 16384
// one-shot blocks — probing the persistent ~215us of non-GEMM time.
// ---------------------------------------------------------------------------
#define PREP_BLOCKS 2048
#define DQ_UNITS (N_DIM * (K_DIM / 2) / 4)  // 2,097,152 int4 units (16B)
#define CVT_UNITS (M_DIM * K_DIM / 4)       // 8,388,608 float4 units (16B)

__global__ __launch_bounds__(256) void prep_kernel(
    const int* __restrict__ packed, const float* __restrict__ absmax,
    bf16_t* __restrict__ W, const float* __restrict__ x,
    bf16_t* __restrict__ y) {
  const int lane = threadIdx.x & 63;
  const int lutbits = __float_as_int(NF4_LUT[lane & 15]);
  const unsigned stride = PREP_BLOCKS * 256;
  const unsigned t0 = blockIdx.x * 256 + threadIdx.x;

  // Phase A: dequant (each unit: 4 bytes-of-payload -> 8 bf16, 16B store).
  for (unsigned t = t0; t < DQ_UNITS; t += stride) {
    const int row = t >> 9;  // K/2/4 = 512 units per row
    const int c = t & 511;
    const int4 p = ((const int4*)packed)[t];
    const float am = absmax[row];
    bf16x8 v;
#pragma unroll
    for (int q = 0; q < 4; ++q) {
      const int byte = (q == 0 ? p.x : q == 1 ? p.y : q == 2 ? p.z : p.w) & 255;
      const float hi = __int_as_float(
          __builtin_amdgcn_ds_bpermute(((byte >> 4) & 15) << 2, lutbits));
      const float lo = __int_as_float(
          __builtin_amdgcn_ds_bpermute((byte & 15) << 2, lutbits));
      v[2 * q] = (bf16_t)(hi * am);
      v[2 * q + 1] = (bf16_t)(lo * am);
    }
    *((bf16x8*)&W[(size_t)row * K_DIM + c * 8]) = v;
  }

  // Phase B: x f32 -> bf16 (16B load, 8B store, fully dense/coalesced).
  for (unsigned t = t0; t < CVT_UNITS; t += stride) {
    const float4 a = ((const float4*)x)[t];
    bf16x4 v;
    v[0] = (bf16_t)a.x; v[1] = (bf16_t)a.y;
    v[2] = (bf16_t)a.z; v[3] = (bf16_t)a.w;
    *((bf16x4*)&y[(size_t)t * 4]) = v;
  }
}

// ---------------------------------------------------------------------------
// Kernel 2: 256x256x64 2-phase bf16 MFMA GEMM, 16x16x32 shape.
// VERBATIM round-3 structure (best measured: 265us, MfmaUtil 44.5%,
// conflicts 0). Round-4's fence removal + slot-reuse interleave regressed
// 28% — the explicit lgkmcnt(0)+sched_barrier fenced structure is the
// empirical optimum; do not re-remove the fences.
//
// LDS: [2 buf][256 rows][8 chunks of 16B], phys chunk = logical ^ (row&7).
// Linear LDS dest for global_load_lds; pre-swizzled GLOBAL source.
// Fragment geometry: row = base + i*16 + l15, slot = (kc*4+quad)^l7 —
// measured 0 bank conflicts (rounds 1/3); round-2's l31-based geometry
// measured 2.5e7 — do not reintroduce without a 32-lane-corrected key.
//
// Per K-tile t (2 barriers, counted vmcnt):
//   p0: read af0-3 (A1-half, 8x b128) + bq (all B, 8x b128);
//       stage A2B2(t+1) -> other buf; BARRIER; lgkmcnt(0); 32 MFMA.
//   p1: read af4-7; stage A1B1(t+2) -> cur buf (read-before-stage separation
//       via the p0 barrier); lgkmcnt(0); 32 MFMA; vmcnt(4)  [retires tile
//       t+1 staging, keeps A1B1(t+2) in flight — never vmcnt(0) mid-loop];
//       BARRIER.
// ---------------------------------------------------------------------------
#define GLD_LDS16(g, l)                                                     \
  __builtin_amdgcn_global_load_lds(                                        \
      (const __attribute__((address_space(1))) void*)(g),                   \
      (__attribute__((address_space(3))) void*)(l), 16, 0, 0)

#define MFMA16(a, b, c) \
  __builtin_amdgcn_mfma_f32_16x16x32_bf16((a), (b), (c), 0, 0, 0)

#define STAGE_A1(tt, lds)                                    \
  do {                                                       \
    GLD_LDS16(gA1a + (size_t)(tt) * 64, (lds) + dA0);        \
    GLD_LDS16(gA1b + (size_t)(tt) * 64, (lds) + dA0 + 16384);\
  } while (0)
#define STAGE_A2(tt, lds)                                    \
  do {                                                       \
    GLD_LDS16(gA2a + (size_t)(tt) * 64, (lds) + dA0 + 8192); \
    GLD_LDS16(gA2b + (size_t)(tt) * 64, (lds) + dA0 + 24576);\
  } while (0)
#define STAGE_B1(tt, lds)                                    \
  do {                                                       \
    GLD_LDS16(gB1a + (size_t)(tt) * 64, (lds) + dB0);        \
    GLD_LDS16(gB1b + (size_t)(tt) * 64, (lds) + dB0 + 16384);\
  } while (0)
#define STAGE_B2(tt, lds)                                    \
  do {                                                       \
    GLD_LDS16(gB2a + (size_t)(tt) * 64, (lds) + dB0 + 4096); \
    GLD_LDS16(gB2b + (size_t)(tt) * 64, (lds) + dB0 + 20480);\
  } while (0)

#define BARRIER()                    \
  asm volatile("" ::: "memory");     \
  __builtin_amdgcn_s_barrier();      \
  asm volatile("" ::: "memory")

#define LGKM0_FENCE()                                   \
  asm volatile("s_waitcnt lgkmcnt(0)" ::: "memory");    \
  __builtin_amdgcn_sched_barrier(0)

__global__ __launch_bounds__(512, 2) void gemm_nf4_kernel(
    const bf16_t* __restrict__ A, const bf16_t* __restrict__ B,
    const float* __restrict__ bias, float* __restrict__ C) {
  constexpr int NT = K_DIM / 64;
  __shared__ __align__(16) bf16_t sA[2][256 * 64];  // 2 x 32 KiB
  __shared__ __align__(16) bf16_t sB[2][256 * 64];  // 2 x 32 KiB

  const int tid = threadIdx.x;
  const int wave = tid >> 6, lane = tid & 63;
  const int wm = wave >> 2, wn = wave & 3;  // 2 x 4 wave grid
  const int quad = lane >> 4, l15 = lane & 15, l7 = lane & 7;

  // T1: XCD-aware block swizzle (512 blocks, 512 % 8 == 0 -> bijective).
  const int id = (blockIdx.x & 7) * 64 + (blockIdx.x >> 3);
  const int blockM = (id & 31) * 256;  // 32 M-blocks
  const int blockN = (id >> 5) * 256;  // 16 N-blocks

  // ---- staging addresses (linear LDS dest, pre-swizzled global source) ----
  const int rqa = tid >> 3;                       // row in 64-row quarter
  const int cira = ((tid & 7) ^ (rqa & 7)) * 8;   // swizzled chunk -> elements
  const bf16_t* gA1a = A + (size_t)(blockM + rqa) * K_DIM + cira;
  const bf16_t* gA1b = gA1a + (size_t)128 * K_DIM;
  const bf16_t* gA2a = gA1a + (size_t)64 * K_DIM;
  const bf16_t* gA2b = gA1a + (size_t)192 * K_DIM;
  const int s0 = tid >> 8, cis = tid & 255;       // B: strip, chunk-in-strip
  const int rqb = cis >> 3;                       // row in 32-row strip
  const int cirb = ((cis & 7) ^ (rqb & 7)) * 8;
  const bf16_t* gB1a = B + (size_t)(blockN + s0 * 64 + rqb) * K_DIM + cirb;
  const bf16_t* gB1b = gB1a + (size_t)128 * K_DIM;
  const bf16_t* gB2a = gB1a + (size_t)32 * K_DIM;
  const bf16_t* gB2b = gB1a + (size_t)160 * K_DIM;
  const int dA0 = tid * 16;
  const int dB0 = s0 * 8192 + cis * 16;

  // ---- fragment-read byte offsets (0-conflict geometry, rounds 1/3) ----
  const int aBase = (wm * 128 + l15) * 128;
  const int bBase = (wn * 64 + l15) * 128;
  const int sl0 = (quad ^ l7) * 16;        // kc = 0
  const int sl1 = ((4 | quad) ^ l7) * 16;  // kc = 1

  f32x4 acc[8][4];
#pragma unroll
  for (int i = 0; i < 8; ++i)
#pragma unroll
    for (int j = 0; j < 4; ++j) acc[i][j] = (f32x4)(0.0f);

  // ---- prologue: tile 0 fully + tile 1's A1/B1 groups ----
  {
    char* sa0 = (char*)sA[0];
    char* sb0 = (char*)sB[0];
    char* sa1 = (char*)sA[1];
    char* sb1 = (char*)sB[1];
    STAGE_A1(0, sa0);
    STAGE_B1(0, sb0);
    STAGE_A2(0, sa0);
    STAGE_B2(0, sb0);
    STAGE_A1(1, sa1);
    STAGE_B1(1, sb1);
    asm volatile("s_waitcnt vmcnt(4)" ::: "memory");  // tile 0 resident
    __builtin_amdgcn_s_barrier();
    asm volatile("" ::: "memory");
  }

  for (int t = 0; t < NT; ++t) {
    char* sa = (char*)sA[t & 1];
    char* sao = (char*)sA[(t + 1) & 1];
    char* sb = (char*)sB[t & 1];
    char* sbo = (char*)sB[(t + 1) & 1];

    bf16x8 af[4][2], bq[4][2];

    // ===== phase 0: A rows (wm*128 + 0..63) + ALL B; stage A2/B2(t+1) =====
#pragma unroll
    for (int i = 0; i < 4; ++i) {
      af[i][0] = *(const bf16x8*)(sa + aBase + i * 2048 + sl0);
      af[i][1] = *(const bf16x8*)(sa + aBase + i * 2048 + sl1);
    }
#pragma unroll
    for (int j = 0; j < 4; ++j) {
      bq[j][0] = *(const bf16x8*)(sb + bBase + j * 2048 + sl0);
      bq[j][1] = *(const bf16x8*)(sb + bBase + j * 2048 + sl1);
    }
    if (t + 1 < NT) {
      STAGE_A2(t + 1, sao);
      STAGE_B2(t + 1, sbo);
    }
    BARRIER();  // mid: all waves' A1/B1(cur) reads issued
    LGKM0_FENCE();
    __builtin_amdgcn_s_setprio(1);
#pragma unroll
    for (int i = 0; i < 4; ++i)
#pragma unroll
      for (int j = 0; j < 4; ++j) {
        acc[i][j] = MFMA16(af[i][0], bq[j][0], acc[i][j]);
        acc[i][j] = MFMA16(af[i][1], bq[j][1], acc[i][j]);
      }
    __builtin_amdgcn_s_setprio(0);

    // ===== phase 1 (no barrier): A rows +64; reuse bq; stage A1/B1(t+2) ====
#pragma unroll
    for (int i = 0; i < 4; ++i) {
      af[i][0] = *(const bf16x8*)(sa + aBase + 8192 + i * 2048 + sl0);
      af[i][1] = *(const bf16x8*)(sa + aBase + 8192 + i * 2048 + sl1);
    }
    if (t + 2 < NT) {
      STAGE_A1(t + 2, sa);
      STAGE_B1(t + 2, sb);
    }
    LGKM0_FENCE();
    __builtin_amdgcn_s_setprio(1);
#pragma unroll
    for (int i = 0; i < 4; ++i)
#pragma unroll
      for (int j = 0; j < 4; ++j) {
        acc[4 + i][j] = MFMA16(af[i][0], bq[j][0], acc[4 + i][j]);
        acc[4 + i][j] = MFMA16(af[i][1], bq[j][1], acc[4 + i][j]);
      }
    __builtin_amdgcn_s_setprio(0);
    // Counted vmcnt (T4): retire tile-(t+1) staging, keep A1B1(t+2) in
    // flight. Full drain only at the pipeline tail.
    if (t < NT - 2)
      asm volatile("s_waitcnt vmcnt(4)" ::: "memory");
    else
      asm volatile("s_waitcnt vmcnt(0)" ::: "memory");
    BARRIER();
  }

  // ---- epilogue: C/D layout col = l15 (n), row = quad*4 + reg (m) ----
#pragma unroll
  for (int j = 0; j < 4; ++j) {
    const int n = blockN + wn * 64 + j * 16 + l15;
    const float bv = bias[n];
#pragma unroll
    for (int i = 0; i < 8; ++i) {
      const int m0 = blockM + wm * 128 + i * 16 + quad * 4;
      f32x4 v = acc[i][j];
      C[(size_t)(m0 + 0) * N_DIM + n] = v[0] + bv;
      C[(size_t)(m0 + 1) * N_DIM + n] = v[1] + bv;
      C[(size_t)(m0 + 2) * N_DIM + n] = v[2] + bv;
      C[(size_t)(m0 + 3) * N_DIM + n] = v[3] + bv;
    }
  }
}

// ---------------------------------------------------------------------------
// Fallback (ws too small): naive on-the-fly dequant GEMM.
// ---------------------------------------------------------------------------
__global__ __launch_bounds__(256) void fallback_kernel(
    const float* __restrict__ x, const int* __restrict__ packed,
    const float* __restrict__ absmax, const float* __restrict__ bias,
    float* __restrict__ out) {
  const int idx = blockIdx.x * 256 + threadIdx.x;
  const int m = idx / N_DIM, n = idx % N_DIM;
  const int* prow = packed + (size_t)n * (K_DIM / 2);
  const float* xr = x + (size_t)m * K_DIM;
  float s = 0.0f;
  for (int p = 0; p < K_DIM / 2; ++p) {
    const int b = prow[p] & 255;
    s += xr[2 * p] * NF4_LUT[(b >> 4) & 15] + xr[2 * p + 1] * NF4_LUT[b & 15];
  }
  out[idx] = s * absmax[n] + bias[n];
}

extern "C" void kernel_launch(void* const* d_in, const int* in_sizes, int n_in,
                              void* d_out, int out_size, void* d_ws,
                              size_t ws_size, hipStream_t stream) {
  const float* x = (const float*)d_in[0];
  const int* packed = (const int*)d_in[1];
  const float* absmax = (const float*)d_in[2];
  const float* bias = (const float*)d_in[3];
  float* out = (float*)d_out;

  const size_t wBytes = (size_t)N_DIM * K_DIM * sizeof(bf16_t);  // 32 MB
  const size_t xBytes = (size_t)M_DIM * K_DIM * sizeof(bf16_t);  // 64 MB
  if (ws_size < wBytes + xBytes) {
    fallback_kernel<<<dim3((M_DIM * N_DIM) / 256), dim3(256), 0, stream>>>(
        x, packed, absmax, bias, out);
    return;
  }

  bf16_t* W = (bf16_t*)d_ws;
  bf16_t* xb = (bf16_t*)((char*)d_ws + wBytes);

  prep_kernel<<<dim3(PREP_BLOCKS), dim3(256), 0, stream>>>(
      packed, absmax, W, x, xb);
  gemm_nf4_kernel<<<dim3((M_DIM / 256) * (N_DIM / 256)), dim3(512), 0,
                    stream>>>(xb, W, bias, out);
}